// Round 1
// baseline (1018.944 us; speedup 1.0000x reference)
//
#include <hip/hip_runtime.h>
#include <hip/hip_bf16.h>
#include <math.h>

// Problem constants (fixed by setup_inputs)
#define BB   4
#define DD   1024
#define TT   2048
#define NH   8
#define DKH  128
#define NROI 128

// Workspace layout (in floats). Total = 9,175,040 floats = 36.7 MB.
#define OFF_Q    0                       // [B, D]            4096
#define OFF_NQ   4096                    // [B, H]            32
#define OFF_P    8192                    // [B*H, T]          65536
#define OFF_KV   131072                  // [B, D, T]         8388608 (K, then overwritten by val)
#define OFF_POOL (131072 + 8388608)      // pooled, all 4 scales: 655360

// ---------------------------------------------------------------------------
// Kernel 1: q = cls @ Wq^T + bq.  Block = (b, 4 consecutive d), warp per d.
__global__ __launch_bounds__(256) void qproj_kernel(
    const float* __restrict__ cls, const float* __restrict__ Wq,
    const float* __restrict__ bq, float* __restrict__ q)
{
    const int blk  = blockIdx.x;          // b*256 + dgroup
    const int b    = blk >> 8;
    const int dg   = blk & 255;
    const int warp = threadIdx.x >> 6;
    const int lane = threadIdx.x & 63;
    const int d    = dg * 4 + warp;
    const float* crow = cls + (size_t)b * DD;
    const float* wrow = Wq + (size_t)d * DD;
    float acc = 0.f;
    for (int i = lane; i < DD; i += 64) acc += crow[i] * wrow[i];
    #pragma unroll
    for (int off = 32; off; off >>= 1) acc += __shfl_down(acc, off);
    if (lane == 0) q[(size_t)b * DD + d] = acc + bq[d];
}

// Kernel 1b: nq[b,h] = ||q[b, h*128 : (h+1)*128]||
__global__ __launch_bounds__(64) void nq_kernel(
    const float* __restrict__ q, float* __restrict__ nq)
{
    const int bh = blockIdx.x;            // b*8 + h
    const int lane = threadIdx.x;
    const float* base = q + (size_t)bh * DKH;   // b*D + h*128 == bh*128
    float v0 = base[lane], v1 = base[lane + 64];
    float acc = v0 * v0 + v1 * v1;
    #pragma unroll
    for (int off = 32; off; off >>= 1) acc += __shfl_down(acc, off);
    if (lane == 0) nq[bh] = sqrtf(acc);
}

// ---------------------------------------------------------------------------
// Kernel 2/4: out[b][m][t] = sum_d W[m][d] * inp[b][d][t] + bias[m]
// MODE 0: write raw (K projection).
// MODE 1: multiply by p_attn[b*8 + m/128][t] (V projection -> val).
// Tiles: 64x64 output, BK=16, 256 threads, 4x4 micro-tile, float4 LDS reads.
template<int MODE>
__global__ __launch_bounds__(256) void proj_gemm(
    const float* __restrict__ inp, const float* __restrict__ W,
    const float* __restrict__ bias, const float* __restrict__ p_attn,
    float* __restrict__ out)
{
    const int t0 = blockIdx.x * 64;
    const int m0 = blockIdx.y * 64;
    const int b  = blockIdx.z;

    __shared__ float As[16][68];   // [k][m], padded: conflict-free writes, 16B-aligned rows
    __shared__ float Bs[16][64];   // [k][t]

    const int tid = threadIdx.x;
    const int tx = tid & 15, ty = tid >> 4;
    float acc[4][4] = {};

    const float* inpB = inp + (size_t)b * DD * TT;

    for (int k0 = 0; k0 < DD; k0 += 16) {
        #pragma unroll
        for (int i = 0; i < 4; ++i) {
            const int li = tid + i * 256;
            const int m = li >> 4, k = li & 15;
            As[k][m] = W[(size_t)(m0 + m) * DD + k0 + k];
        }
        #pragma unroll
        for (int i = 0; i < 4; ++i) {
            const int li = tid + i * 256;
            const int k = li >> 6, t = li & 63;
            Bs[k][t] = inpB[(size_t)(k0 + k) * TT + t0 + t];
        }
        __syncthreads();
        #pragma unroll
        for (int k = 0; k < 16; ++k) {
            const float4 av = *reinterpret_cast<const float4*>(&As[k][ty * 4]);
            const float4 bv = *reinterpret_cast<const float4*>(&Bs[k][tx * 4]);
            const float a[4] = {av.x, av.y, av.z, av.w};
            const float bb[4] = {bv.x, bv.y, bv.z, bv.w};
            #pragma unroll
            for (int i = 0; i < 4; ++i)
                #pragma unroll
                for (int jj = 0; jj < 4; ++jj)
                    acc[i][jj] = fmaf(a[i], bb[jj], acc[i][jj]);
        }
        __syncthreads();
    }

    const int m_base = m0 + ty * 4;
    const int t_base = t0 + tx * 4;
    float pv[4] = {1.f, 1.f, 1.f, 1.f};
    if (MODE == 1) {
        // whole 64-row tile lies within one head: head = m0 >> 7
        const float* prow = p_attn + (size_t)(b * NH + (m0 >> 7)) * TT + t_base;
        pv[0] = prow[0]; pv[1] = prow[1]; pv[2] = prow[2]; pv[3] = prow[3];
    }
    #pragma unroll
    for (int i = 0; i < 4; ++i) {
        const float bi = bias[m_base + i];
        float4 r;
        r.x = (acc[i][0] + bi) * pv[0];
        r.y = (acc[i][1] + bi) * pv[1];
        r.z = (acc[i][2] + bi) * pv[2];
        r.w = (acc[i][3] + bi) * pv[3];
        *reinterpret_cast<float4*>(&out[(size_t)(b * DD + m_base + i) * TT + t_base]) = r;
    }
}

// ---------------------------------------------------------------------------
// Kernel 3: p_attn[b,h,t] = exp(|dot(q_h, k_h_t) / max(nq*nk, eps)|)
// Block = (64 t, one (b,h)); threads = 4 d-groups x 64 t-lanes.
__global__ __launch_bounds__(256) void attn_kernel(
    const float* __restrict__ K, const float* __restrict__ q,
    const float* __restrict__ nq, float* __restrict__ p)
{
    const int t0 = blockIdx.x * 64;
    const int h  = blockIdx.y;
    const int b  = blockIdx.z;

    __shared__ float qs[DKH];
    __shared__ float pdot[4][64];
    __shared__ float psq[4][64];

    const int tid = threadIdx.x;
    if (tid < DKH) qs[tid] = q[(size_t)b * DD + h * DKH + tid];
    __syncthreads();

    const int dg = tid >> 6, tl = tid & 63;
    const float* Kb = K + ((size_t)(b * DD + h * DKH)) * TT + t0 + tl;
    float dot = 0.f, sq = 0.f;
    #pragma unroll 4
    for (int d = dg * 32; d < dg * 32 + 32; ++d) {
        const float kv = Kb[(size_t)d * TT];
        dot += kv * qs[d];
        sq  += kv * kv;
    }
    pdot[dg][tl] = dot;
    psq[dg][tl]  = sq;
    __syncthreads();
    if (tid < 64) {
        const float dd = pdot[0][tid] + pdot[1][tid] + pdot[2][tid] + pdot[3][tid];
        const float ss = psq[0][tid] + psq[1][tid] + psq[2][tid] + psq[3][tid];
        const float nk = sqrtf(ss);
        const float c  = dd / fmaxf(nq[b * NH + h] * nk, 1e-8f);
        p[(size_t)(b * NH + h) * TT + t0 + tid] = expf(fabsf(c));
    }
}

// ---------------------------------------------------------------------------
// Kernel 5: ROI adaptive avg pool. Block = (n, scale j). 4 waves = 4 channels
// in flight, 64 t-lanes each, shuffle-reduce per (channel, bin).
__global__ __launch_bounds__(256) void pool_kernel(
    const float* __restrict__ val, const int* __restrict__ rois,
    float* __restrict__ pooled)
{
    const int n  = blockIdx.x;
    const int sc = blockIdx.y;
    int nb, off;
    switch (sc) {
        case 0:  nb = 1; off = 0;      break;
        case 1:  nb = 3; off = 32768;  break;
        case 2:  nb = 7; off = 131072; break;
        default: nb = 9; off = 360448; break;
    }
    const int bidx = rois[n * 3 + 0];
    const int s    = rois[n * 3 + 1];
    const int e    = rois[n * 3 + 2];
    const int L    = e - s;

    const int cq = threadIdx.x >> 6;    // wave id -> channel within group of 4
    const int tl = threadIdx.x & 63;
    const float* vb = val + ((size_t)(bidx * DD + sc * 256)) * TT;

    for (int bin = 0; bin < nb; ++bin) {
        const int bs  = s + (bin * L) / nb;
        const int be  = s + ((bin + 1) * L + nb - 1) / nb;
        const int cnt = max(be - bs, 1);
        const float inv = 1.0f / (float)cnt;
        for (int co = 0; co < 64; ++co) {
            const int c = co * 4 + cq;
            const float* row = vb + (size_t)c * TT;
            float acc = 0.f;
            for (int t = bs + tl; t < be; t += 64) acc += row[t];
            #pragma unroll
            for (int o2 = 32; o2; o2 >>= 1) acc += __shfl_down(acc, o2);
            if (tl == 0)
                pooled[off + ((size_t)n * 256 + c) * nb + bin] = acc * inv;
        }
    }
}

// ---------------------------------------------------------------------------
// Kernel 6: out[n, sc*256 + o] = sum_k pooled_sc[n,k] * Wsc[o,k] + bsc[o]
// NT GEMM, 32x32 tile, 256 threads, 2x2 micro-tile, k-tile 32.
__global__ __launch_bounds__(256) void out_gemm(
    const float* __restrict__ pooled,
    const float* __restrict__ w1, const float* __restrict__ b1,
    const float* __restrict__ w3, const float* __restrict__ b3,
    const float* __restrict__ w7, const float* __restrict__ b7,
    const float* __restrict__ w9, const float* __restrict__ b9,
    float* __restrict__ out)
{
    const int sc = blockIdx.z;
    int nb, off; const float* W; const float* bias;
    switch (sc) {
        case 0:  nb = 1; off = 0;      W = w1; bias = b1; break;
        case 1:  nb = 3; off = 32768;  W = w3; bias = b3; break;
        case 2:  nb = 7; off = 131072; W = w7; bias = b7; break;
        default: nb = 9; off = 360448; W = w9; bias = b9; break;
    }
    const int Kj = 256 * nb;
    const float* P = pooled + off;

    const int o0 = blockIdx.x * 32;
    const int n0 = blockIdx.y * 32;

    __shared__ float Ps[32][33];
    __shared__ float Ws[32][33];

    const int tid = threadIdx.x;
    const int tx = tid & 15, ty = tid >> 4;
    float acc[2][2] = {};

    for (int k0 = 0; k0 < Kj; k0 += 32) {
        #pragma unroll
        for (int i = 0; i < 4; ++i) {
            const int li = tid + i * 256;
            const int r = li >> 5, k = li & 31;
            Ps[r][k] = P[(size_t)(n0 + r) * Kj + k0 + k];
            Ws[r][k] = W[(size_t)(o0 + r) * Kj + k0 + k];
        }
        __syncthreads();
        #pragma unroll
        for (int k = 0; k < 32; ++k) {
            const float p0 = Ps[ty][k],      p1 = Ps[ty + 16][k];
            const float w0 = Ws[tx][k],      w1v = Ws[tx + 16][k];
            acc[0][0] = fmaf(p0, w0,  acc[0][0]);
            acc[0][1] = fmaf(p0, w1v, acc[0][1]);
            acc[1][0] = fmaf(p1, w0,  acc[1][0]);
            acc[1][1] = fmaf(p1, w1v, acc[1][1]);
        }
        __syncthreads();
    }
    #pragma unroll
    for (int i = 0; i < 2; ++i) {
        const int n = n0 + ty + 16 * i;
        #pragma unroll
        for (int jj = 0; jj < 2; ++jj) {
            const int o = o0 + tx + 16 * jj;
            out[(size_t)n * DD + sc * 256 + o] = acc[i][jj] + bias[o];
        }
    }
}

// ---------------------------------------------------------------------------
extern "C" void kernel_launch(void* const* d_in, const int* in_sizes, int n_in,
                              void* d_out, int out_size, void* d_ws, size_t ws_size,
                              hipStream_t stream)
{
    const float* inp  = (const float*)d_in[0];   // [B, D, T]
    const float* cls  = (const float*)d_in[1];   // [B, D]
    const int*   rois = (const int*)  d_in[2];   // [N, 3]
    const float* Wq   = (const float*)d_in[3];
    const float* bq   = (const float*)d_in[4];
    const float* Wk   = (const float*)d_in[5];
    const float* bk   = (const float*)d_in[6];
    const float* Wv   = (const float*)d_in[7];
    const float* bv   = (const float*)d_in[8];
    const float* cw1  = (const float*)d_in[9];  const float* cb1 = (const float*)d_in[10];
    const float* cw3  = (const float*)d_in[11]; const float* cb3 = (const float*)d_in[12];
    const float* cw7  = (const float*)d_in[13]; const float* cb7 = (const float*)d_in[14];
    const float* cw9  = (const float*)d_in[15]; const float* cb9 = (const float*)d_in[16];

    float* out = (float*)d_out;
    float* ws  = (float*)d_ws;
    float* q      = ws + OFF_Q;
    float* nq     = ws + OFF_NQ;
    float* p      = ws + OFF_P;
    float* KV     = ws + OFF_KV;     // K first, then overwritten by val
    float* pooled = ws + OFF_POOL;

    qproj_kernel<<<dim3(BB * 256), 256, 0, stream>>>(cls, Wq, bq, q);
    nq_kernel<<<dim3(BB * NH), 64, 0, stream>>>(q, nq);
    proj_gemm<0><<<dim3(TT / 64, DD / 64, BB), 256, 0, stream>>>(inp, Wk, bk, nullptr, KV);
    attn_kernel<<<dim3(TT / 64, NH, BB), 256, 0, stream>>>(KV, q, nq, p);
    proj_gemm<1><<<dim3(TT / 64, DD / 64, BB), 256, 0, stream>>>(inp, Wv, bv, p, KV);
    pool_kernel<<<dim3(NROI, 4), 256, 0, stream>>>(KV, rois, pooled);
    out_gemm<<<dim3(8, 4, 4), 256, 0, stream>>>(pooled, cw1, cb1, cw3, cb3,
                                                cw7, cb7, cw9, cb9, out);
}

// Round 2
// 277.946 us; speedup vs baseline: 3.6660x; 3.6660x over previous
//
#include <hip/hip_runtime.h>
#include <hip/hip_bf16.h>
#include <math.h>

// Problem constants (fixed by setup_inputs)
#define BB   4
#define DD   1024
#define TT   2048
#define NH   8
#define DKH  128
#define NROI 128

typedef __attribute__((ext_vector_type(8))) __bf16 bf16x8;
typedef __attribute__((ext_vector_type(4))) float  f32x4;

// Workspace layout.
// fp32 region (floats):
#define OFF_Q    0                       // [B, D]            4096
#define OFF_NQ   4096                    // [B, H]            32
#define OFF_P    8192                    // [B*H, T]          65536
#define OFF_KV   131072                  // [B, D, T]         8388608 (K, then val)
#define OFF_POOL (131072 + 8388608)      // pooled: 655360
#define WS_F32_TOTAL (OFF_POOL + 655360) // 9,175,040 floats = 36.7 MB
// bf16 region starts at ws + WS_F32_TOTAL (as __hip_bfloat16*):
//   Wkb [1024*1024], Wvb [1024*1024], Xt [B*T*D] = 2MB+2MB+16MB -> total 57.7MB

// ---------------------------------------------------------------------------
// Kernel 1: q = cls @ Wq^T + bq (fp32, tiny)
__global__ __launch_bounds__(256) void qproj_kernel(
    const float* __restrict__ cls, const float* __restrict__ Wq,
    const float* __restrict__ bq, float* __restrict__ q)
{
    const int blk  = blockIdx.x;
    const int b    = blk >> 8;
    const int dg   = blk & 255;
    const int warp = threadIdx.x >> 6;
    const int lane = threadIdx.x & 63;
    const int d    = dg * 4 + warp;
    const float* crow = cls + (size_t)b * DD;
    const float* wrow = Wq + (size_t)d * DD;
    float acc = 0.f;
    for (int i = lane; i < DD; i += 64) acc += crow[i] * wrow[i];
    #pragma unroll
    for (int off = 32; off; off >>= 1) acc += __shfl_down(acc, off);
    if (lane == 0) q[(size_t)b * DD + d] = acc + bq[d];
}

__global__ __launch_bounds__(64) void nq_kernel(
    const float* __restrict__ q, float* __restrict__ nq)
{
    const int bh = blockIdx.x;
    const int lane = threadIdx.x;
    const float* base = q + (size_t)bh * DKH;
    float v0 = base[lane], v1 = base[lane + 64];
    float acc = v0 * v0 + v1 * v1;
    #pragma unroll
    for (int off = 32; off; off >>= 1) acc += __shfl_down(acc, off);
    if (lane == 0) nq[bh] = sqrtf(acc);
}

// ---------------------------------------------------------------------------
// Convert two fp32 weight matrices to bf16 (1M elements each), float4-wide.
__global__ __launch_bounds__(256) void convert_pair(
    const float* __restrict__ A, const float* __restrict__ B,
    __hip_bfloat16* __restrict__ Ab, __hip_bfloat16* __restrict__ Bb)
{
    const int i = blockIdx.x * 256 + threadIdx.x;   // quad index, 262144 total
    float4 a = reinterpret_cast<const float4*>(A)[i];
    float4 b = reinterpret_cast<const float4*>(B)[i];
    union P4 { __hip_bfloat16 h[4]; ushort4 u; } pa, pb;
    pa.h[0] = __float2bfloat16(a.x); pa.h[1] = __float2bfloat16(a.y);
    pa.h[2] = __float2bfloat16(a.z); pa.h[3] = __float2bfloat16(a.w);
    pb.h[0] = __float2bfloat16(b.x); pb.h[1] = __float2bfloat16(b.y);
    pb.h[2] = __float2bfloat16(b.z); pb.h[3] = __float2bfloat16(b.w);
    reinterpret_cast<ushort4*>(Ab)[i] = pa.u;
    reinterpret_cast<ushort4*>(Bb)[i] = pb.u;
}

// ---------------------------------------------------------------------------
// X [B][D][T] f32 -> Xt [B][T][D] bf16 (transpose + convert), 64x64 tiles.
__global__ __launch_bounds__(256) void transpose_convert(
    const float* __restrict__ X, __hip_bfloat16* __restrict__ Xt)
{
    __shared__ float tile[64][65];
    const int t0 = blockIdx.x * 64, d0 = blockIdx.y * 64, b = blockIdx.z;
    const int tl = threadIdx.x & 63;
    const int g  = threadIdx.x >> 6;
    const float* src = X + ((size_t)(b * DD + d0)) * TT + t0;
    #pragma unroll
    for (int i = 0; i < 16; ++i) {
        const int d = g * 16 + i;
        tile[d][tl] = src[(size_t)d * TT + tl];
    }
    __syncthreads();
    __hip_bfloat16* dst = Xt + ((size_t)(b * TT + t0)) * DD + d0;
    #pragma unroll
    for (int i = 0; i < 16; ++i) {
        const int t = g * 16 + i;
        dst[(size_t)t * DD + tl] = __float2bfloat16(tile[tl][t]);
    }
}

// ---------------------------------------------------------------------------
// bf16 MFMA projection: out[b][m][t] = sum_d W[m][d]*Xt[b][t][d] + bias[m]
// MODE 1: multiply by p_attn[b*8 + m>>7][t].
// 128x128 tile, BK=32, 256 threads (4 waves, 2x2 of 64x64 each),
// global_load_lds(16B) staging with XOR-swizzled k-slot (2-way-free ds_read_b128).
__device__ __forceinline__ void glds16(const __hip_bfloat16* g, __hip_bfloat16* l)
{
    __builtin_amdgcn_global_load_lds(
        (const __attribute__((address_space(1))) void*)g,
        (__attribute__((address_space(3))) void*)l, 16, 0, 0);
}

template<int MODE>
__global__ __launch_bounds__(256) void proj_mfma(
    const __hip_bfloat16* __restrict__ Wb,   // [1024][1024]
    const __hip_bfloat16* __restrict__ Xt,   // [B][T][D]
    const float* __restrict__ bias,
    const float* __restrict__ p_attn,        // [B*H][T]
    float* __restrict__ out)                 // [B][D][T]
{
    const int t0 = blockIdx.x * 128;
    const int m0 = blockIdx.y * 128;
    const int b  = blockIdx.z;

    __shared__ __hip_bfloat16 As[128 * 32];  // W tile [row=m][32 k], swizzled slots
    __shared__ __hip_bfloat16 Bs[128 * 32];  // Xt tile [row=t][32 k], swizzled slots

    const int tid  = threadIdx.x;
    const int lane = tid & 63;
    const int w    = tid >> 6;
    const int wr   = w >> 1, wc = w & 1;

    // staging: per wave-issue 16 rows x 32 k (1024B). lane -> row st_row, slot s=lane&3.
    // slot s stores k-group g = s ^ ((row>>1)&3); with 16-row-aligned bases this is
    // g = (lane&3) ^ ((lane>>3)&3).
    const int st_row = lane >> 2;
    const int st_g   = (lane & 3) ^ ((lane >> 3) & 3);

    const __hip_bfloat16* Wsrc = Wb + (size_t)(m0 + w * 32 + st_row) * DD + st_g * 8;
    const __hip_bfloat16* Xsrc = Xt + ((size_t)(b * TT + t0 + w * 32 + st_row)) * DD + st_g * 8;
    __hip_bfloat16* AsD0 = As + (w * 32) * 32;
    __hip_bfloat16* AsD1 = As + (w * 32 + 16) * 32;
    __hip_bfloat16* BsD0 = Bs + (w * 32) * 32;
    __hip_bfloat16* BsD1 = Bs + (w * 32 + 16) * 32;

    f32x4 acc[4][4];
    #pragma unroll
    for (int i = 0; i < 4; ++i)
        #pragma unroll
        for (int j = 0; j < 4; ++j)
            acc[i][j] = (f32x4){0.f, 0.f, 0.f, 0.f};

    for (int k0 = 0; k0 < DD; k0 += 32) {
        glds16(Wsrc + k0,            AsD0);
        glds16(Wsrc + k0 + 16 * DD,  AsD1);
        glds16(Xsrc + k0,            BsD0);
        glds16(Xsrc + k0 + 16 * DD,  BsD1);
        __syncthreads();   // compiler emits vmcnt(0) before s_barrier

        bf16x8 af[4], bfr[4];
        const int g = lane >> 4;
        #pragma unroll
        for (int fm = 0; fm < 4; ++fm) {
            const int r = wr * 64 + fm * 16 + (lane & 15);
            const int s = g ^ ((r >> 1) & 3);
            af[fm] = *reinterpret_cast<const bf16x8*>(&As[r * 32 + s * 8]);
        }
        #pragma unroll
        for (int fn = 0; fn < 4; ++fn) {
            const int r = wc * 64 + fn * 16 + (lane & 15);
            const int s = g ^ ((r >> 1) & 3);
            bfr[fn] = *reinterpret_cast<const bf16x8*>(&Bs[r * 32 + s * 8]);
        }
        #pragma unroll
        for (int fm = 0; fm < 4; ++fm)
            #pragma unroll
            for (int fn = 0; fn < 4; ++fn)
                acc[fm][fn] = __builtin_amdgcn_mfma_f32_16x16x32_bf16(
                    af[fm], bfr[fn], acc[fm][fn], 0, 0, 0);
        __syncthreads();
    }

    // Epilogue. C/D: col(t) = lane&15, row(m) = (lane>>4)*4 + reg.
    const int head = m0 >> 7;   // 128-row tile lies in one head
    const float* prow = p_attn + ((size_t)(b * NH + head)) * TT;
    const int tcol = t0 + wc * 64 + (lane & 15);
    float pv[4];
    #pragma unroll
    for (int fn = 0; fn < 4; ++fn)
        pv[fn] = (MODE == 1) ? prow[tcol + fn * 16] : 1.f;

    #pragma unroll
    for (int fm = 0; fm < 4; ++fm) {
        const int mb = m0 + wr * 64 + fm * 16 + (lane >> 4) * 4;
        #pragma unroll
        for (int r = 0; r < 4; ++r) {
            const int m = mb + r;
            const float bi = bias[m];
            float* orow = out + ((size_t)(b * DD + m)) * TT;
            #pragma unroll
            for (int fn = 0; fn < 4; ++fn)
                orow[tcol + fn * 16] = (acc[fm][fn][r] + bi) * pv[fn];
        }
    }
}

// ---------------------------------------------------------------------------
// Kernel 3: p_attn[b,h,t] = exp(|dot(q_h, k_h_t) / max(nq*nk, eps)|)
__global__ __launch_bounds__(256) void attn_kernel(
    const float* __restrict__ K, const float* __restrict__ q,
    const float* __restrict__ nq, float* __restrict__ p)
{
    const int t0 = blockIdx.x * 64;
    const int h  = blockIdx.y;
    const int b  = blockIdx.z;

    __shared__ float qs[DKH];
    __shared__ float pdot[4][64];
    __shared__ float psq[4][64];

    const int tid = threadIdx.x;
    if (tid < DKH) qs[tid] = q[(size_t)b * DD + h * DKH + tid];
    __syncthreads();

    const int dg = tid >> 6, tl = tid & 63;
    const float* Kb = K + ((size_t)(b * DD + h * DKH)) * TT + t0 + tl;
    float dot = 0.f, sq = 0.f;
    #pragma unroll 4
    for (int d = dg * 32; d < dg * 32 + 32; ++d) {
        const float kv = Kb[(size_t)d * TT];
        dot += kv * qs[d];
        sq  += kv * kv;
    }
    pdot[dg][tl] = dot;
    psq[dg][tl]  = sq;
    __syncthreads();
    if (tid < 64) {
        const float dd = pdot[0][tid] + pdot[1][tid] + pdot[2][tid] + pdot[3][tid];
        const float ss = psq[0][tid] + psq[1][tid] + psq[2][tid] + psq[3][tid];
        const float nk = sqrtf(ss);
        const float c  = dd / fmaxf(nq[b * NH + h] * nk, 1e-8f);
        p[(size_t)(b * NH + h) * TT + t0 + tid] = expf(fabsf(c));
    }
}

// ---------------------------------------------------------------------------
// Kernel 5: ROI pool — one thread per (roi, channel). No cross-lane reduce.
// Block = (n, sc), 256 threads = 256 channels of that scale.
__global__ __launch_bounds__(256) void pool_kernel(
    const float* __restrict__ val, const int* __restrict__ rois,
    float* __restrict__ pooled)
{
    const int n  = blockIdx.x;
    const int sc = blockIdx.y;
    int nb, off;
    switch (sc) {
        case 0:  nb = 1; off = 0;      break;
        case 1:  nb = 3; off = 32768;  break;
        case 2:  nb = 7; off = 131072; break;
        default: nb = 9; off = 360448; break;
    }
    const int bidx = rois[n * 3 + 0];
    const int s    = rois[n * 3 + 1];
    const int e    = rois[n * 3 + 2];
    const int L    = e - s;

    const int c = threadIdx.x;
    const float* row = val + ((size_t)(bidx * DD + sc * 256 + c)) * TT;
    float* po = pooled + off + ((size_t)n * 256 + c) * nb;

    for (int bin = 0; bin < nb; ++bin) {
        const int bs  = s + (bin * L) / nb;
        const int be  = s + ((bin + 1) * L + nb - 1) / nb;
        const int cnt = max(be - bs, 1);
        float acc = 0.f;
        int t = bs;
        for (; t < be && (t & 3); ++t) acc += row[t];
        float a0 = 0.f, a1 = 0.f, a2 = 0.f, a3 = 0.f;
        for (; t + 4 <= be; t += 4) {
            const float4 v = *reinterpret_cast<const float4*>(row + t);
            a0 += v.x; a1 += v.y; a2 += v.z; a3 += v.w;
        }
        acc += (a0 + a1) + (a2 + a3);
        for (; t < be; ++t) acc += row[t];
        po[bin] = acc / (float)cnt;
    }
}

// ---------------------------------------------------------------------------
// Kernel 6: final NT GEMM per scale.
__global__ __launch_bounds__(256) void out_gemm(
    const float* __restrict__ pooled,
    const float* __restrict__ w1, const float* __restrict__ b1,
    const float* __restrict__ w3, const float* __restrict__ b3,
    const float* __restrict__ w7, const float* __restrict__ b7,
    const float* __restrict__ w9, const float* __restrict__ b9,
    float* __restrict__ out)
{
    const int sc = blockIdx.z;
    int nb, off; const float* W; const float* bias;
    switch (sc) {
        case 0:  nb = 1; off = 0;      W = w1; bias = b1; break;
        case 1:  nb = 3; off = 32768;  W = w3; bias = b3; break;
        case 2:  nb = 7; off = 131072; W = w7; bias = b7; break;
        default: nb = 9; off = 360448; W = w9; bias = b9; break;
    }
    const int Kj = 256 * nb;
    const float* P = pooled + off;

    const int o0 = blockIdx.x * 32;
    const int n0 = blockIdx.y * 32;

    __shared__ float Ps[32][33];
    __shared__ float Ws[32][33];

    const int tid = threadIdx.x;
    const int tx = tid & 15, ty = tid >> 4;
    float acc[2][2] = {};

    for (int k0 = 0; k0 < Kj; k0 += 32) {
        #pragma unroll
        for (int i = 0; i < 4; ++i) {
            const int li = tid + i * 256;
            const int r = li >> 5, k = li & 31;
            Ps[r][k] = P[(size_t)(n0 + r) * Kj + k0 + k];
            Ws[r][k] = W[(size_t)(o0 + r) * Kj + k0 + k];
        }
        __syncthreads();
        #pragma unroll
        for (int k = 0; k < 32; ++k) {
            const float p0 = Ps[ty][k],  p1 = Ps[ty + 16][k];
            const float w0 = Ws[tx][k],  w1v = Ws[tx + 16][k];
            acc[0][0] = fmaf(p0, w0,  acc[0][0]);
            acc[0][1] = fmaf(p0, w1v, acc[0][1]);
            acc[1][0] = fmaf(p1, w0,  acc[1][0]);
            acc[1][1] = fmaf(p1, w1v, acc[1][1]);
        }
        __syncthreads();
    }
    #pragma unroll
    for (int i = 0; i < 2; ++i) {
        const int n = n0 + ty + 16 * i;
        #pragma unroll
        for (int jj = 0; jj < 2; ++jj) {
            const int o = o0 + tx + 16 * jj;
            out[(size_t)n * DD + sc * 256 + o] = acc[i][jj] + bias[o];
        }
    }
}

// ---------------------------------------------------------------------------
extern "C" void kernel_launch(void* const* d_in, const int* in_sizes, int n_in,
                              void* d_out, int out_size, void* d_ws, size_t ws_size,
                              hipStream_t stream)
{
    const float* inp  = (const float*)d_in[0];   // [B, D, T]
    const float* cls  = (const float*)d_in[1];   // [B, D]
    const int*   rois = (const int*)  d_in[2];   // [N, 3]
    const float* Wq   = (const float*)d_in[3];
    const float* bq   = (const float*)d_in[4];
    const float* Wk   = (const float*)d_in[5];
    const float* bk   = (const float*)d_in[6];
    const float* Wv   = (const float*)d_in[7];
    const float* bv   = (const float*)d_in[8];
    const float* cw1  = (const float*)d_in[9];  const float* cb1 = (const float*)d_in[10];
    const float* cw3  = (const float*)d_in[11]; const float* cb3 = (const float*)d_in[12];
    const float* cw7  = (const float*)d_in[13]; const float* cb7 = (const float*)d_in[14];
    const float* cw9  = (const float*)d_in[15]; const float* cb9 = (const float*)d_in[16];

    float* out = (float*)d_out;
    float* ws  = (float*)d_ws;
    float* q      = ws + OFF_Q;
    float* nq     = ws + OFF_NQ;
    float* p      = ws + OFF_P;
    float* KV     = ws + OFF_KV;     // K (fp32), then overwritten by val
    float* pooled = ws + OFF_POOL;
    __hip_bfloat16* bfb = (__hip_bfloat16*)(ws + WS_F32_TOTAL);
    __hip_bfloat16* Wkb = bfb;                      // 1,048,576
    __hip_bfloat16* Wvb = bfb + 1048576;            // 1,048,576
    __hip_bfloat16* Xt  = bfb + 2097152;            // B*T*D = 8,388,608

    convert_pair<<<dim3(1024), 256, 0, stream>>>(Wk, Wv, Wkb, Wvb);
    transpose_convert<<<dim3(TT / 64, DD / 64, BB), 256, 0, stream>>>(inp, Xt);
    qproj_kernel<<<dim3(BB * 256), 256, 0, stream>>>(cls, Wq, bq, q);
    nq_kernel<<<dim3(BB * NH), 64, 0, stream>>>(q, nq);
    proj_mfma<0><<<dim3(TT / 128, DD / 128, BB), 256, 0, stream>>>(Wkb, Xt, bk, nullptr, KV);
    attn_kernel<<<dim3(TT / 64, NH, BB), 256, 0, stream>>>(KV, q, nq, p);
    proj_mfma<1><<<dim3(TT / 128, DD / 128, BB), 256, 0, stream>>>(Wvb, Xt, bv, p, KV);
    pool_kernel<<<dim3(NROI, 4), 256, 0, stream>>>(KV, rois, pooled);
    out_gemm<<<dim3(8, 4, 4), 256, 0, stream>>>(pooled, cw1, cb1, cw3, cb3,
                                                cw7, cb7, cw9, cb9, out);
}

// Round 3
// 242.124 us; speedup vs baseline: 4.2084x; 1.1479x over previous
//
#include <hip/hip_runtime.h>
#include <hip/hip_bf16.h>
#include <math.h>

// Problem constants (fixed by setup_inputs)
#define BB   4
#define DD   1024
#define TT   2048
#define NH   8
#define DKH  128
#define NROI 128

typedef __attribute__((ext_vector_type(8))) __bf16 bf16x8;
typedef __attribute__((ext_vector_type(4))) float  f32x4;

// Workspace layout.
// fp32 region (floats):
#define OFF_Q    0                       // [B, D]            4096
#define OFF_NQ   4096                    // [B, H]            32
#define OFF_P    8192                    // [B*H, T]          65536
#define OFF_KV   131072                  // K fp32 [B][T][D] 8388608 floats; later val bf16 (16MB) reuses it
#define OFF_POOL (131072 + 8388608)      // pooled: 655360 floats
#define POOL_FLOATS 655360
#define WS_F32_TOTAL (OFF_POOL + POOL_FLOATS) // 9,175,040 floats = 36.7 MB
// bf16 region at ws + WS_F32_TOTAL: Wkb [1M], Wvb [1M], Xt [8M] = 20 MB. Total ~57.7 MB.

__device__ __forceinline__ float bfu2f(unsigned short u) {
    return __uint_as_float(((unsigned int)u) << 16);
}

// ---------------------------------------------------------------------------
// Kernel 1: q = cls @ Wq^T + bq (fp32, tiny)
__global__ __launch_bounds__(256) void qproj_kernel(
    const float* __restrict__ cls, const float* __restrict__ Wq,
    const float* __restrict__ bq, float* __restrict__ q)
{
    const int blk  = blockIdx.x;
    const int b    = blk >> 8;
    const int dg   = blk & 255;
    const int warp = threadIdx.x >> 6;
    const int lane = threadIdx.x & 63;
    const int d    = dg * 4 + warp;
    const float* crow = cls + (size_t)b * DD;
    const float* wrow = Wq + (size_t)d * DD;
    float acc = 0.f;
    for (int i = lane; i < DD; i += 64) acc += crow[i] * wrow[i];
    #pragma unroll
    for (int off = 32; off; off >>= 1) acc += __shfl_down(acc, off);
    if (lane == 0) q[(size_t)b * DD + d] = acc + bq[d];
}

__global__ __launch_bounds__(64) void nq_kernel(
    const float* __restrict__ q, float* __restrict__ nq)
{
    const int bh = blockIdx.x;
    const int lane = threadIdx.x;
    const float* base = q + (size_t)bh * DKH;
    float v0 = base[lane], v1 = base[lane + 64];
    float acc = v0 * v0 + v1 * v1;
    #pragma unroll
    for (int off = 32; off; off >>= 1) acc += __shfl_down(acc, off);
    if (lane == 0) nq[bh] = sqrtf(acc);
}

// ---------------------------------------------------------------------------
// Convert two fp32 weight matrices to bf16 (1M elements each), float4-wide.
__global__ __launch_bounds__(256) void convert_pair(
    const float* __restrict__ A, const float* __restrict__ B,
    __hip_bfloat16* __restrict__ Ab, __hip_bfloat16* __restrict__ Bb)
{
    const int i = blockIdx.x * 256 + threadIdx.x;   // quad index, 262144 total
    float4 a = reinterpret_cast<const float4*>(A)[i];
    float4 b = reinterpret_cast<const float4*>(B)[i];
    union P4 { __hip_bfloat16 h[4]; ushort4 u; } pa, pb;
    pa.h[0] = __float2bfloat16(a.x); pa.h[1] = __float2bfloat16(a.y);
    pa.h[2] = __float2bfloat16(a.z); pa.h[3] = __float2bfloat16(a.w);
    pb.h[0] = __float2bfloat16(b.x); pb.h[1] = __float2bfloat16(b.y);
    pb.h[2] = __float2bfloat16(b.z); pb.h[3] = __float2bfloat16(b.w);
    reinterpret_cast<ushort4*>(Ab)[i] = pa.u;
    reinterpret_cast<ushort4*>(Bb)[i] = pb.u;
}

// ---------------------------------------------------------------------------
// X [B][D][T] f32 -> Xt [B][T][D] bf16. Loads coalesced scalar (256B/instr),
// writes vectorized ushort4 (4 full 128B rows per wave per step).
__global__ __launch_bounds__(256) void transpose_convert(
    const float* __restrict__ X, __hip_bfloat16* __restrict__ Xt)
{
    __shared__ float tile[64][65];
    const int t0 = blockIdx.x * 64, d0 = blockIdx.y * 64, b = blockIdx.z;
    const int tid = threadIdx.x;
    const int g = tid >> 6, tl = tid & 63;
    const float* src = X + ((size_t)(b * DD + d0)) * TT + t0;
    #pragma unroll
    for (int i = 0; i < 16; ++i)
        tile[g * 16 + i][tl] = src[(size_t)(g * 16 + i) * TT + tl];
    __syncthreads();
    const int lane = tid & 63, w = tid >> 6;
    const int dq = (lane & 15) * 4;
    const int th = lane >> 4;          // 0..3
    __hip_bfloat16* dst = Xt + ((size_t)(b * TT + t0)) * DD + d0;
    #pragma unroll
    for (int i = 0; i < 4; ++i) {
        const int t = w * 4 + th + i * 16;
        union { __hip_bfloat16 h[4]; ushort4 u; } P;
        P.h[0] = __float2bfloat16(tile[dq + 0][t]);
        P.h[1] = __float2bfloat16(tile[dq + 1][t]);
        P.h[2] = __float2bfloat16(tile[dq + 2][t]);
        P.h[3] = __float2bfloat16(tile[dq + 3][t]);
        *reinterpret_cast<ushort4*>(&dst[(size_t)t * DD + dq]) = P.u;
    }
}

// ---------------------------------------------------------------------------
// bf16 MFMA projection, output [B][T][D]:
//   MODE 0: K fp32:  K[b][t][m]  = sum_d W[m][d]*Xt[b][t][d] + bias[m]
//   MODE 1: val bf16: val[b][t][m] = (proj + bias[m]) * p_attn[b*8 + m>>7][t]
// 128x128 tile, BK=32, 256 threads (4 waves, 2x2 of 64x64 each),
// global_load_lds(16B) staging with XOR-swizzled k-slot.
__device__ __forceinline__ void glds16(const __hip_bfloat16* g, __hip_bfloat16* l)
{
    __builtin_amdgcn_global_load_lds(
        (const __attribute__((address_space(1))) void*)g,
        (__attribute__((address_space(3))) void*)l, 16, 0, 0);
}

template<int MODE>
__global__ __launch_bounds__(256) void proj_mfma(
    const __hip_bfloat16* __restrict__ Wb,   // [1024][1024]
    const __hip_bfloat16* __restrict__ Xt,   // [B][T][D]
    const float* __restrict__ bias,
    const float* __restrict__ p_attn,        // [B*H][T]
    float* __restrict__ outF,                // MODE 0: [B][T][D] fp32
    __hip_bfloat16* __restrict__ outH)       // MODE 1: [B][T][D] bf16
{
    const int t0 = blockIdx.x * 128;
    const int m0 = blockIdx.y * 128;
    const int b  = blockIdx.z;

    __shared__ __hip_bfloat16 As[128 * 32];  // W tile, swizzled slots
    __shared__ __hip_bfloat16 Bs[128 * 32];  // Xt tile, swizzled slots

    const int tid  = threadIdx.x;
    const int lane = tid & 63;
    const int w    = tid >> 6;
    const int wr   = w >> 1, wc = w & 1;

    const int st_row = lane >> 2;
    const int st_g   = (lane & 3) ^ ((lane >> 3) & 3);

    const __hip_bfloat16* Wsrc = Wb + (size_t)(m0 + w * 32 + st_row) * DD + st_g * 8;
    const __hip_bfloat16* Xsrc = Xt + ((size_t)(b * TT + t0 + w * 32 + st_row)) * DD + st_g * 8;
    __hip_bfloat16* AsD0 = As + (w * 32) * 32;
    __hip_bfloat16* AsD1 = As + (w * 32 + 16) * 32;
    __hip_bfloat16* BsD0 = Bs + (w * 32) * 32;
    __hip_bfloat16* BsD1 = Bs + (w * 32 + 16) * 32;

    f32x4 acc[4][4];
    #pragma unroll
    for (int i = 0; i < 4; ++i)
        #pragma unroll
        for (int j = 0; j < 4; ++j)
            acc[i][j] = (f32x4){0.f, 0.f, 0.f, 0.f};

    for (int k0 = 0; k0 < DD; k0 += 32) {
        glds16(Wsrc + k0,            AsD0);
        glds16(Wsrc + k0 + 16 * DD,  AsD1);
        glds16(Xsrc + k0,            BsD0);
        glds16(Xsrc + k0 + 16 * DD,  BsD1);
        __syncthreads();

        bf16x8 af[4], bfr[4];
        const int g = lane >> 4;
        #pragma unroll
        for (int fm = 0; fm < 4; ++fm) {
            const int r = wr * 64 + fm * 16 + (lane & 15);
            const int s = g ^ ((r >> 1) & 3);
            af[fm] = *reinterpret_cast<const bf16x8*>(&As[r * 32 + s * 8]);
        }
        #pragma unroll
        for (int fn = 0; fn < 4; ++fn) {
            const int r = wc * 64 + fn * 16 + (lane & 15);
            const int s = g ^ ((r >> 1) & 3);
            bfr[fn] = *reinterpret_cast<const bf16x8*>(&Bs[r * 32 + s * 8]);
        }
        #pragma unroll
        for (int fm = 0; fm < 4; ++fm)
            #pragma unroll
            for (int fn = 0; fn < 4; ++fn)
                acc[fm][fn] = __builtin_amdgcn_mfma_f32_16x16x32_bf16(
                    af[fm], bfr[fn], acc[fm][fn], 0, 0, 0);
        __syncthreads();
    }

    // Epilogue. C/D: col(t) = lane&15, row(m) = (lane>>4)*4 + reg.
    // Output [B][T][D]: the 4 regs are m-consecutive -> vector stores.
    const int head  = m0 >> 7;
    const int tbase = t0 + wc * 64 + (lane & 15);
    float pv[4];
    #pragma unroll
    for (int fn = 0; fn < 4; ++fn)
        pv[fn] = (MODE == 1)
            ? p_attn[((size_t)(b * NH + head)) * TT + tbase + fn * 16] : 1.f;

    #pragma unroll
    for (int fm = 0; fm < 4; ++fm) {
        const int m = m0 + wr * 64 + fm * 16 + (lane >> 4) * 4;
        const float4 b4 = *reinterpret_cast<const float4*>(&bias[m]);
        #pragma unroll
        for (int fn = 0; fn < 4; ++fn) {
            const int t = tbase + fn * 16;
            const f32x4 a = acc[fm][fn];
            if (MODE == 0) {
                float4 r;
                r.x = a[0] + b4.x; r.y = a[1] + b4.y;
                r.z = a[2] + b4.z; r.w = a[3] + b4.w;
                *reinterpret_cast<float4*>(&outF[((size_t)(b * TT + t)) * DD + m]) = r;
            } else {
                const float pf = pv[fn];
                union { __hip_bfloat16 h[4]; ushort4 u; } P;
                P.h[0] = __float2bfloat16((a[0] + b4.x) * pf);
                P.h[1] = __float2bfloat16((a[1] + b4.y) * pf);
                P.h[2] = __float2bfloat16((a[2] + b4.z) * pf);
                P.h[3] = __float2bfloat16((a[3] + b4.w) * pf);
                *reinterpret_cast<ushort4*>(&outH[((size_t)(b * TT + t)) * DD + m]) = P.u;
            }
        }
    }
}

// ---------------------------------------------------------------------------
// Kernel 3: p_attn[b,h,t] = exp(|cos|). K is [B][T][D]: one thread per (t, h)
// reads 128 contiguous floats. No cross-lane reduction.
__global__ __launch_bounds__(256) void attn_kernel(
    const float* __restrict__ K, const float* __restrict__ q,
    const float* __restrict__ nq, float* __restrict__ p)
{
    const int t0 = blockIdx.x * 32;
    const int b  = blockIdx.y;
    __shared__ float qs[DD];
    const int tid = threadIdx.x;
    *reinterpret_cast<float4*>(&qs[tid * 4]) =
        *reinterpret_cast<const float4*>(&q[(size_t)b * DD + tid * 4]);
    __syncthreads();

    const int tl = tid >> 3;        // 0..31
    const int h  = tid & 7;
    const int t  = t0 + tl;
    const float4* krow = reinterpret_cast<const float4*>(
        K + ((size_t)(b * TT + t)) * DD + h * DKH);
    const float4* qrow = reinterpret_cast<const float4*>(qs + h * DKH);
    float dot = 0.f, sq = 0.f;
    #pragma unroll 8
    for (int j = 0; j < 32; ++j) {
        const float4 kv = krow[j];
        const float4 qv = qrow[j];
        dot += kv.x * qv.x + kv.y * qv.y + kv.z * qv.z + kv.w * qv.w;
        sq  += kv.x * kv.x + kv.y * kv.y + kv.z * kv.z + kv.w * kv.w;
    }
    const float nk = sqrtf(sq);
    const float c  = dot / fmaxf(nq[b * NH + h] * nk, 1e-8f);
    p[((size_t)(b * NH + h)) * TT + t] = expf(fabsf(c));
}

// ---------------------------------------------------------------------------
// Kernel 5: ROI pool over val [B][T][D] bf16. Grid (NROI, TSPLIT).
// Threads cover all 1024 channels (4/thread, ushort4 coalesced). Per-bin
// segmented t-loop (single float4 accumulator), atomicAdd prescaled partials.
#define TSPLIT 8
__global__ __launch_bounds__(256) void pool_kernel(
    const __hip_bfloat16* __restrict__ val, const int* __restrict__ rois,
    float* __restrict__ pooled)
{
    const int n     = blockIdx.x;
    const int split = blockIdx.y;
    const int tid   = threadIdx.x;
    const int sc    = tid >> 6;            // wave-uniform scale
    const int c4    = tid * 4;             // global channel base
    const int cl    = (tid & 63) * 4;      // channel within scale

    const int nbt[4]  = {1, 3, 7, 9};
    const int offt[4] = {0, 32768, 131072, 360448};
    const int nb  = nbt[sc];
    const int off = offt[sc];

    const int bidx = rois[n * 3 + 0];
    const int s    = rois[n * 3 + 1];
    const int e    = rois[n * 3 + 2];
    const int L    = e - s;

    const int ts = s + (split * L) / TSPLIT;
    const int te = s + ((split + 1) * L) / TSPLIT;
    if (te <= ts) return;

    // bins overlapping [ts, te): b_lo = bin containing ts, b_hi = last bin
    // containing te-1 (bins can overlap by one element).
    const int b_lo = ((ts - s) * nb) / L;
    const int b_hi = ((te - s) * nb - 1) / L;

    const __hip_bfloat16* vb = val + (size_t)bidx * TT * DD + c4;
    float* po = pooled + off + ((size_t)n * 256 + cl) * nb;

    for (int bin = b_lo; bin <= b_hi; ++bin) {
        const int bs = s + (bin * L) / nb;
        const int be = s + ((bin + 1) * L + nb - 1) / nb;
        const int lo = max(bs, ts), hi = min(be, te);
        if (hi <= lo) continue;
        float a0 = 0.f, a1 = 0.f, a2 = 0.f, a3 = 0.f;
        for (int t = lo; t < hi; ++t) {
            const ushort4 u = *reinterpret_cast<const ushort4*>(&vb[(size_t)t * DD]);
            a0 += bfu2f(u.x); a1 += bfu2f(u.y);
            a2 += bfu2f(u.z); a3 += bfu2f(u.w);
        }
        const float inv = 1.0f / (float)(be - bs);
        atomicAdd(po + bin,          a0 * inv);
        atomicAdd(po + nb + bin,     a1 * inv);
        atomicAdd(po + 2 * nb + bin, a2 * inv);
        atomicAdd(po + 3 * nb + bin, a3 * inv);
    }
}

// ---------------------------------------------------------------------------
// Kernel 6: final NT GEMM per scale.
__global__ __launch_bounds__(256) void out_gemm(
    const float* __restrict__ pooled,
    const float* __restrict__ w1, const float* __restrict__ b1,
    const float* __restrict__ w3, const float* __restrict__ b3,
    const float* __restrict__ w7, const float* __restrict__ b7,
    const float* __restrict__ w9, const float* __restrict__ b9,
    float* __restrict__ out)
{
    const int sc = blockIdx.z;
    int nb, off; const float* W; const float* bias;
    switch (sc) {
        case 0:  nb = 1; off = 0;      W = w1; bias = b1; break;
        case 1:  nb = 3; off = 32768;  W = w3; bias = b3; break;
        case 2:  nb = 7; off = 131072; W = w7; bias = b7; break;
        default: nb = 9; off = 360448; W = w9; bias = b9; break;
    }
    const int Kj = 256 * nb;
    const float* P = pooled + off;

    const int o0 = blockIdx.x * 32;
    const int n0 = blockIdx.y * 32;

    __shared__ float Ps[32][33];
    __shared__ float Ws[32][33];

    const int tid = threadIdx.x;
    const int tx = tid & 15, ty = tid >> 4;
    float acc[2][2] = {};

    for (int k0 = 0; k0 < Kj; k0 += 32) {
        #pragma unroll
        for (int i = 0; i < 4; ++i) {
            const int li = tid + i * 256;
            const int r = li >> 5, k = li & 31;
            Ps[r][k] = P[(size_t)(n0 + r) * Kj + k0 + k];
            Ws[r][k] = W[(size_t)(o0 + r) * Kj + k0 + k];
        }
        __syncthreads();
        #pragma unroll
        for (int k = 0; k < 32; ++k) {
            const float p0 = Ps[ty][k],  p1 = Ps[ty + 16][k];
            const float w0 = Ws[tx][k],  w1v = Ws[tx + 16][k];
            acc[0][0] = fmaf(p0, w0,  acc[0][0]);
            acc[0][1] = fmaf(p0, w1v, acc[0][1]);
            acc[1][0] = fmaf(p1, w0,  acc[1][0]);
            acc[1][1] = fmaf(p1, w1v, acc[1][1]);
        }
        __syncthreads();
    }
    #pragma unroll
    for (int i = 0; i < 2; ++i) {
        const int n = n0 + ty + 16 * i;
        #pragma unroll
        for (int jj = 0; jj < 2; ++jj) {
            const int o = o0 + tx + 16 * jj;
            out[(size_t)n * DD + sc * 256 + o] = acc[i][jj] + bias[o];
        }
    }
}

// ---------------------------------------------------------------------------
extern "C" void kernel_launch(void* const* d_in, const int* in_sizes, int n_in,
                              void* d_out, int out_size, void* d_ws, size_t ws_size,
                              hipStream_t stream)
{
    const float* inp  = (const float*)d_in[0];   // [B, D, T]
    const float* cls  = (const float*)d_in[1];   // [B, D]
    const int*   rois = (const int*)  d_in[2];   // [N, 3]
    const float* Wq   = (const float*)d_in[3];
    const float* bq   = (const float*)d_in[4];
    const float* Wk   = (const float*)d_in[5];
    const float* bk   = (const float*)d_in[6];
    const float* Wv   = (const float*)d_in[7];
    const float* bv   = (const float*)d_in[8];
    const float* cw1  = (const float*)d_in[9];  const float* cb1 = (const float*)d_in[10];
    const float* cw3  = (const float*)d_in[11]; const float* cb3 = (const float*)d_in[12];
    const float* cw7  = (const float*)d_in[13]; const float* cb7 = (const float*)d_in[14];
    const float* cw9  = (const float*)d_in[15]; const float* cb9 = (const float*)d_in[16];

    float* out = (float*)d_out;
    float* ws  = (float*)d_ws;
    float* q      = ws + OFF_Q;
    float* nq     = ws + OFF_NQ;
    float* p      = ws + OFF_P;
    float* K      = ws + OFF_KV;                       // fp32 [B][T][D]
    __hip_bfloat16* val = (__hip_bfloat16*)(ws + OFF_KV);  // bf16 [B][T][D], reuses K after attn
    float* pooled = ws + OFF_POOL;
    __hip_bfloat16* bfb = (__hip_bfloat16*)(ws + WS_F32_TOTAL);
    __hip_bfloat16* Wkb = bfb;
    __hip_bfloat16* Wvb = bfb + 1048576;
    __hip_bfloat16* Xt  = bfb + 2097152;               // [B][T][D]

    convert_pair<<<dim3(1024), 256, 0, stream>>>(Wk, Wv, Wkb, Wvb);
    transpose_convert<<<dim3(TT / 64, DD / 64, BB), 256, 0, stream>>>(inp, Xt);
    qproj_kernel<<<dim3(BB * 256), 256, 0, stream>>>(cls, Wq, bq, q);
    nq_kernel<<<dim3(BB * NH), 64, 0, stream>>>(q, nq);
    proj_mfma<0><<<dim3(TT / 128, DD / 128, BB), 256, 0, stream>>>(
        Wkb, Xt, bk, nullptr, K, nullptr);
    attn_kernel<<<dim3(TT / 32, BB), 256, 0, stream>>>(K, q, nq, p);
    proj_mfma<1><<<dim3(TT / 128, DD / 128, BB), 256, 0, stream>>>(
        Wvb, Xt, bv, p, nullptr, val);
    hipMemsetAsync(pooled, 0, POOL_FLOATS * sizeof(float), stream);
    pool_kernel<<<dim3(NROI, TSPLIT), 256, 0, stream>>>(val, rois, pooled);
    out_gemm<<<dim3(8, 4, 4), 256, 0, stream>>>(pooled, cw1, cb1, cw3, cb3,
                                                cw7, cb7, cw9, cb9, out);
}

// Round 4
// 198.779 us; speedup vs baseline: 5.1260x; 1.2181x over previous
//
#include <hip/hip_runtime.h>
#include <hip/hip_bf16.h>
#include <math.h>

// Problem constants (fixed by setup_inputs)
#define BB   4
#define DD   1024
#define TT   2048
#define NH   8
#define DKH  128
#define NROI 128

typedef __attribute__((ext_vector_type(8))) __bf16 bf16x8;
typedef __attribute__((ext_vector_type(4))) float  f32x4;

// Workspace layout.
// fp32 region (floats):
#define OFF_Q    0                       // [B, D]            4096
#define OFF_NQ   4096                    // [B, H]            32
#define OFF_KV   131072                  // val bf16 [B][T][D] (16MB) lives here
#define OFF_POOL (131072 + 8388608)      // pooled: 655360 floats
#define POOL_FLOATS 655360
#define WS_F32_TOTAL (OFF_POOL + POOL_FLOATS)
// bf16 region at ws + WS_F32_TOTAL: Wkb [1M], Wvb [1M], Xt [8M] = 20 MB.

__device__ __forceinline__ float bfu2f(unsigned short u) {
    return __uint_as_float(((unsigned int)u) << 16);
}

// ---------------------------------------------------------------------------
// Kernel 1: q = cls @ Wq^T + bq (fp32, tiny)
__global__ __launch_bounds__(256) void qproj_kernel(
    const float* __restrict__ cls, const float* __restrict__ Wq,
    const float* __restrict__ bq, float* __restrict__ q)
{
    const int blk  = blockIdx.x;
    const int b    = blk >> 8;
    const int dg   = blk & 255;
    const int warp = threadIdx.x >> 6;
    const int lane = threadIdx.x & 63;
    const int d    = dg * 4 + warp;
    const float* crow = cls + (size_t)b * DD;
    const float* wrow = Wq + (size_t)d * DD;
    float acc = 0.f;
    for (int i = lane; i < DD; i += 64) acc += crow[i] * wrow[i];
    #pragma unroll
    for (int off = 32; off; off >>= 1) acc += __shfl_down(acc, off);
    if (lane == 0) q[(size_t)b * DD + d] = acc + bq[d];
}

__global__ __launch_bounds__(64) void nq_kernel(
    const float* __restrict__ q, float* __restrict__ nq)
{
    const int bh = blockIdx.x;
    const int lane = threadIdx.x;
    const float* base = q + (size_t)bh * DKH;
    float v0 = base[lane], v1 = base[lane + 64];
    float acc = v0 * v0 + v1 * v1;
    #pragma unroll
    for (int off = 32; off; off >>= 1) acc += __shfl_down(acc, off);
    if (lane == 0) nq[bh] = sqrtf(acc);
}

// ---------------------------------------------------------------------------
// Convert two fp32 weight matrices to bf16 (1M elements each), float4-wide.
__global__ __launch_bounds__(256) void convert_pair(
    const float* __restrict__ A, const float* __restrict__ B,
    __hip_bfloat16* __restrict__ Ab, __hip_bfloat16* __restrict__ Bb)
{
    const int i = blockIdx.x * 256 + threadIdx.x;
    float4 a = reinterpret_cast<const float4*>(A)[i];
    float4 b = reinterpret_cast<const float4*>(B)[i];
    union P4 { __hip_bfloat16 h[4]; ushort4 u; } pa, pb;
    pa.h[0] = __float2bfloat16(a.x); pa.h[1] = __float2bfloat16(a.y);
    pa.h[2] = __float2bfloat16(a.z); pa.h[3] = __float2bfloat16(a.w);
    pb.h[0] = __float2bfloat16(b.x); pb.h[1] = __float2bfloat16(b.y);
    pb.h[2] = __float2bfloat16(b.z); pb.h[3] = __float2bfloat16(b.w);
    reinterpret_cast<ushort4*>(Ab)[i] = pa.u;
    reinterpret_cast<ushort4*>(Bb)[i] = pb.u;
}

// ---------------------------------------------------------------------------
// X [B][D][T] f32 -> Xt [B][T][D] bf16.
__global__ __launch_bounds__(256) void transpose_convert(
    const float* __restrict__ X, __hip_bfloat16* __restrict__ Xt)
{
    __shared__ float tile[64][65];
    const int t0 = blockIdx.x * 64, d0 = blockIdx.y * 64, b = blockIdx.z;
    const int tid = threadIdx.x;
    const int g = tid >> 6, tl = tid & 63;
    const float* src = X + ((size_t)(b * DD + d0)) * TT + t0;
    #pragma unroll
    for (int i = 0; i < 16; ++i)
        tile[g * 16 + i][tl] = src[(size_t)(g * 16 + i) * TT + tl];
    __syncthreads();
    const int lane = tid & 63, w = tid >> 6;
    const int dq = (lane & 15) * 4;
    const int th = lane >> 4;
    __hip_bfloat16* dst = Xt + ((size_t)(b * TT + t0)) * DD + d0;
    #pragma unroll
    for (int i = 0; i < 4; ++i) {
        const int t = w * 4 + th + i * 16;
        union { __hip_bfloat16 h[4]; ushort4 u; } P;
        P.h[0] = __float2bfloat16(tile[dq + 0][t]);
        P.h[1] = __float2bfloat16(tile[dq + 1][t]);
        P.h[2] = __float2bfloat16(tile[dq + 2][t]);
        P.h[3] = __float2bfloat16(tile[dq + 3][t]);
        *reinterpret_cast<ushort4*>(&dst[(size_t)t * DD + dq]) = P.u;
    }
}

// ---------------------------------------------------------------------------
__device__ __forceinline__ void glds16(const __hip_bfloat16* g, __hip_bfloat16* l)
{
    __builtin_amdgcn_global_load_lds(
        (const __attribute__((address_space(1))) void*)g,
        (__attribute__((address_space(3))) void*)l, 16, 0, 0);
}

// Fused K-proj + cosine-attn + V-proj:
//   k[t][m] = sum_d Wk[m][d]*Xt[b][t][d] + bk[m]        (m-tile = one head h)
//   dot(t)  = sum_m k[t][m]*q[b][m0+m];  sq(t) = sum_m k[t][m]^2   (block-local!)
//   p(t)    = exp(|dot / max(nq[b,h]*sqrt(sq), eps)|)
//   val[b][t][m] = bf16((sum_d Wv[m][d]*Xt[b][t][d] + bv[m]) * p(t))
// 128x128 tile, BK=32, 4 waves (2x2 of 64x64), 3 staged LDS tiles.
__global__ __launch_bounds__(256) void fused_kv(
    const __hip_bfloat16* __restrict__ Wkb,
    const __hip_bfloat16* __restrict__ Wvb,
    const __hip_bfloat16* __restrict__ Xt,
    const float* __restrict__ bk, const float* __restrict__ bv,
    const float* __restrict__ q,  const float* __restrict__ nq,
    __hip_bfloat16* __restrict__ val)
{
    const int t0 = blockIdx.x * 128;
    const int m0 = blockIdx.y * 128;
    const int b  = blockIdx.z;

    __shared__ __hip_bfloat16 AsK[128 * 32];
    __shared__ __hip_bfloat16 AsV[128 * 32];
    __shared__ __hip_bfloat16 Bs[128 * 32];
    __shared__ float qs[128];
    __shared__ float rdot[2][2][64];   // [wc][wr][t_local in half]
    __shared__ float rsq[2][2][64];
    __shared__ float p_lds[128];

    const int tid  = threadIdx.x;
    const int lane = tid & 63;
    const int w    = tid >> 6;
    const int wr   = w >> 1, wc = w & 1;

    if (tid < 128) qs[tid] = q[(size_t)b * DD + m0 + tid];

    const int st_row = lane >> 2;
    const int st_g   = (lane & 3) ^ ((lane >> 3) & 3);

    const __hip_bfloat16* WkS = Wkb + (size_t)(m0 + w * 32 + st_row) * DD + st_g * 8;
    const __hip_bfloat16* WvS = Wvb + (size_t)(m0 + w * 32 + st_row) * DD + st_g * 8;
    const __hip_bfloat16* XS  = Xt + ((size_t)(b * TT + t0 + w * 32 + st_row)) * DD + st_g * 8;
    __hip_bfloat16* K0 = AsK + (w * 32) * 32;
    __hip_bfloat16* K1 = AsK + (w * 32 + 16) * 32;
    __hip_bfloat16* V0 = AsV + (w * 32) * 32;
    __hip_bfloat16* V1 = AsV + (w * 32 + 16) * 32;
    __hip_bfloat16* B0 = Bs  + (w * 32) * 32;
    __hip_bfloat16* B1 = Bs  + (w * 32 + 16) * 32;

    f32x4 ak[4][4], av[4][4];
    #pragma unroll
    for (int i = 0; i < 4; ++i)
        #pragma unroll
        for (int j = 0; j < 4; ++j) {
            ak[i][j] = (f32x4){0.f, 0.f, 0.f, 0.f};
            av[i][j] = (f32x4){0.f, 0.f, 0.f, 0.f};
        }

    for (int k0 = 0; k0 < DD; k0 += 32) {
        glds16(WkS + k0,           K0);
        glds16(WkS + k0 + 16 * DD, K1);
        glds16(WvS + k0,           V0);
        glds16(WvS + k0 + 16 * DD, V1);
        glds16(XS  + k0,           B0);
        glds16(XS  + k0 + 16 * DD, B1);
        __syncthreads();

        const int g = lane >> 4;
        bf16x8 bfx[4], afk[4], afv[4];
        #pragma unroll
        for (int fn = 0; fn < 4; ++fn) {
            const int r = wc * 64 + fn * 16 + (lane & 15);
            const int s = g ^ ((r >> 1) & 3);
            bfx[fn] = *reinterpret_cast<const bf16x8*>(&Bs[r * 32 + s * 8]);
        }
        #pragma unroll
        for (int fm = 0; fm < 4; ++fm) {
            const int r = wr * 64 + fm * 16 + (lane & 15);
            const int s = g ^ ((r >> 1) & 3);
            afk[fm] = *reinterpret_cast<const bf16x8*>(&AsK[r * 32 + s * 8]);
            afv[fm] = *reinterpret_cast<const bf16x8*>(&AsV[r * 32 + s * 8]);
        }
        #pragma unroll
        for (int fm = 0; fm < 4; ++fm)
            #pragma unroll
            for (int fn = 0; fn < 4; ++fn)
                ak[fm][fn] = __builtin_amdgcn_mfma_f32_16x16x32_bf16(
                    afk[fm], bfx[fn], ak[fm][fn], 0, 0, 0);
        #pragma unroll
        for (int fm = 0; fm < 4; ++fm)
            #pragma unroll
            for (int fn = 0; fn < 4; ++fn)
                av[fm][fn] = __builtin_amdgcn_mfma_f32_16x16x32_bf16(
                    afv[fm], bfx[fn], av[fm][fn], 0, 0, 0);
        __syncthreads();
    }

    // --- attention scalar per t (block-local over the head's 128 dims) ---
    // C/D: t_local = wc*64 + fn*16 + (lane&15); m_local = wr*64 + fm*16 + (lane>>4)*4 + r
    const int lg = lane >> 4;
    #pragma unroll
    for (int fn = 0; fn < 4; ++fn) {
        float dp = 0.f, sp = 0.f;
        #pragma unroll
        for (int fm = 0; fm < 4; ++fm) {
            const int mb = wr * 64 + fm * 16 + lg * 4;
            #pragma unroll
            for (int r = 0; r < 4; ++r) {
                const float kv = ak[fm][fn][r] + bk[m0 + mb + r];
                dp += kv * qs[mb + r];
                sp += kv * kv;
            }
        }
        dp += __shfl_xor(dp, 16); sp += __shfl_xor(sp, 16);
        dp += __shfl_xor(dp, 32); sp += __shfl_xor(sp, 32);
        if (lane < 16) {
            rdot[wc][wr][fn * 16 + lane] = dp;
            rsq[wc][wr][fn * 16 + lane]  = sp;
        }
    }
    __syncthreads();
    if (tid < 128) {
        const int wcc = tid >> 6, j = tid & 63;
        const float dd = rdot[wcc][0][j] + rdot[wcc][1][j];
        const float ss = rsq[wcc][0][j] + rsq[wcc][1][j];
        const int head = m0 >> 7;
        const float c = dd / fmaxf(nq[b * NH + head] * sqrtf(ss), 1e-8f);
        p_lds[tid] = expf(fabsf(c));
    }
    __syncthreads();

    // --- val write: (av + bv) * p, bf16, [B][T][D] ---
    float pv[4];
    #pragma unroll
    for (int fn = 0; fn < 4; ++fn)
        pv[fn] = p_lds[wc * 64 + fn * 16 + (lane & 15)];

    const int tbase = t0 + wc * 64 + (lane & 15);
    #pragma unroll
    for (int fm = 0; fm < 4; ++fm) {
        const int m = m0 + wr * 64 + fm * 16 + lg * 4;
        const float4 b4 = *reinterpret_cast<const float4*>(&bv[m]);
        #pragma unroll
        for (int fn = 0; fn < 4; ++fn) {
            const int t = tbase + fn * 16;
            const f32x4 a = av[fm][fn];
            const float pf = pv[fn];
            union { __hip_bfloat16 h[4]; ushort4 u; } P;
            P.h[0] = __float2bfloat16((a[0] + b4.x) * pf);
            P.h[1] = __float2bfloat16((a[1] + b4.y) * pf);
            P.h[2] = __float2bfloat16((a[2] + b4.z) * pf);
            P.h[3] = __float2bfloat16((a[3] + b4.w) * pf);
            *reinterpret_cast<ushort4*>(&val[((size_t)(b * TT + t)) * DD + m]) = P.u;
        }
    }
}

// ---------------------------------------------------------------------------
// ROI pool over val [B][T][D] bf16. Grid (NROI, TSPLIT).
#define TSPLIT 8
__global__ __launch_bounds__(256) void pool_kernel(
    const __hip_bfloat16* __restrict__ val, const int* __restrict__ rois,
    float* __restrict__ pooled)
{
    const int n     = blockIdx.x;
    const int split = blockIdx.y;
    const int tid   = threadIdx.x;
    const int sc    = tid >> 6;
    const int c4    = tid * 4;
    const int cl    = (tid & 63) * 4;

    const int nbt[4]  = {1, 3, 7, 9};
    const int offt[4] = {0, 32768, 131072, 360448};
    const int nb  = nbt[sc];
    const int off = offt[sc];

    const int bidx = rois[n * 3 + 0];
    const int s    = rois[n * 3 + 1];
    const int e    = rois[n * 3 + 2];
    const int L    = e - s;

    const int ts = s + (split * L) / TSPLIT;
    const int te = s + ((split + 1) * L) / TSPLIT;
    if (te <= ts) return;

    const int b_lo = ((ts - s) * nb) / L;
    const int b_hi = ((te - s) * nb - 1) / L;

    const __hip_bfloat16* vb = val + (size_t)bidx * TT * DD + c4;
    float* po = pooled + off + ((size_t)n * 256 + cl) * nb;

    for (int bin = b_lo; bin <= b_hi; ++bin) {
        const int bs = s + (bin * L) / nb;
        const int be = s + ((bin + 1) * L + nb - 1) / nb;
        const int lo = max(bs, ts), hi = min(be, te);
        if (hi <= lo) continue;
        float a0 = 0.f, a1 = 0.f, a2 = 0.f, a3 = 0.f;
        for (int t = lo; t < hi; ++t) {
            const ushort4 u = *reinterpret_cast<const ushort4*>(&vb[(size_t)t * DD]);
            a0 += bfu2f(u.x); a1 += bfu2f(u.y);
            a2 += bfu2f(u.z); a3 += bfu2f(u.w);
        }
        const float inv = 1.0f / (float)(be - bs);
        atomicAdd(po + bin,          a0 * inv);
        atomicAdd(po + nb + bin,     a1 * inv);
        atomicAdd(po + 2 * nb + bin, a2 * inv);
        atomicAdd(po + 3 * nb + bin, a3 * inv);
    }
}

// ---------------------------------------------------------------------------
// Final NT GEMM, K-split for parallelism. Grid (8 o-tiles, 4 n-tiles, 20
// chunks). Chunk z -> (scale, 256-wide k-chunk). atomicAdd partials into out
// (zero-initialized); the kc==0 block adds the bias.
__global__ __launch_bounds__(256) void out_gemm(
    const float* __restrict__ pooled,
    const float* __restrict__ w1, const float* __restrict__ b1,
    const float* __restrict__ w3, const float* __restrict__ b3,
    const float* __restrict__ w7, const float* __restrict__ b7,
    const float* __restrict__ w9, const float* __restrict__ b9,
    float* __restrict__ out)
{
    const int z = blockIdx.z;
    int sc, kc;
    if      (z == 0)  { sc = 0; kc = 0; }
    else if (z < 4)   { sc = 1; kc = z - 1; }
    else if (z < 11)  { sc = 2; kc = z - 4; }
    else              { sc = 3; kc = z - 11; }

    int nb, off; const float* W; const float* bias;
    switch (sc) {
        case 0:  nb = 1; off = 0;      W = w1; bias = b1; break;
        case 1:  nb = 3; off = 32768;  W = w3; bias = b3; break;
        case 2:  nb = 7; off = 131072; W = w7; bias = b7; break;
        default: nb = 9; off = 360448; W = w9; bias = b9; break;
    }
    const int Kj = 256 * nb;
    const float* P = pooled + off;

    const int o0 = blockIdx.x * 32;
    const int n0 = blockIdx.y * 32;
    const int kbase = kc * 256;

    __shared__ float Ps[32][33];
    __shared__ float Ws[32][33];

    const int tid = threadIdx.x;
    const int tx = tid & 15, ty = tid >> 4;
    float acc[2][2] = {};

    for (int k0 = kbase; k0 < kbase + 256; k0 += 32) {
        #pragma unroll
        for (int i = 0; i < 4; ++i) {
            const int li = tid + i * 256;
            const int r = li >> 5, k = li & 31;
            Ps[r][k] = P[(size_t)(n0 + r) * Kj + k0 + k];
            Ws[r][k] = W[(size_t)(o0 + r) * Kj + k0 + k];
        }
        __syncthreads();
        #pragma unroll
        for (int k = 0; k < 32; ++k) {
            const float p0 = Ps[ty][k],  p1 = Ps[ty + 16][k];
            const float w0 = Ws[tx][k],  w1v = Ws[tx + 16][k];
            acc[0][0] = fmaf(p0, w0,  acc[0][0]);
            acc[0][1] = fmaf(p0, w1v, acc[0][1]);
            acc[1][0] = fmaf(p1, w0,  acc[1][0]);
            acc[1][1] = fmaf(p1, w1v, acc[1][1]);
        }
        __syncthreads();
    }
    #pragma unroll
    for (int i = 0; i < 2; ++i) {
        const int n = n0 + ty + 16 * i;
        #pragma unroll
        for (int jj = 0; jj < 2; ++jj) {
            const int o = o0 + tx + 16 * jj;
            const float add = (kc == 0) ? bias[o] : 0.f;
            atomicAdd(&out[(size_t)n * DD + sc * 256 + o], acc[i][jj] + add);
        }
    }
}

// ---------------------------------------------------------------------------
extern "C" void kernel_launch(void* const* d_in, const int* in_sizes, int n_in,
                              void* d_out, int out_size, void* d_ws, size_t ws_size,
                              hipStream_t stream)
{
    const float* inp  = (const float*)d_in[0];   // [B, D, T]
    const float* cls  = (const float*)d_in[1];   // [B, D]
    const int*   rois = (const int*)  d_in[2];   // [N, 3]
    const float* Wq   = (const float*)d_in[3];
    const float* bq   = (const float*)d_in[4];
    const float* Wk   = (const float*)d_in[5];
    const float* bk   = (const float*)d_in[6];
    const float* Wv   = (const float*)d_in[7];
    const float* bv   = (const float*)d_in[8];
    const float* cw1  = (const float*)d_in[9];  const float* cb1 = (const float*)d_in[10];
    const float* cw3  = (const float*)d_in[11]; const float* cb3 = (const float*)d_in[12];
    const float* cw7  = (const float*)d_in[13]; const float* cb7 = (const float*)d_in[14];
    const float* cw9  = (const float*)d_in[15]; const float* cb9 = (const float*)d_in[16];

    float* out = (float*)d_out;
    float* ws  = (float*)d_ws;
    float* q      = ws + OFF_Q;
    float* nq     = ws + OFF_NQ;
    __hip_bfloat16* val = (__hip_bfloat16*)(ws + OFF_KV);  // bf16 [B][T][D]
    float* pooled = ws + OFF_POOL;
    __hip_bfloat16* bfb = (__hip_bfloat16*)(ws + WS_F32_TOTAL);
    __hip_bfloat16* Wkb = bfb;
    __hip_bfloat16* Wvb = bfb + 1048576;
    __hip_bfloat16* Xt  = bfb + 2097152;               // [B][T][D]

    convert_pair<<<dim3(1024), 256, 0, stream>>>(Wk, Wv, Wkb, Wvb);
    transpose_convert<<<dim3(TT / 64, DD / 64, BB), 256, 0, stream>>>(inp, Xt);
    qproj_kernel<<<dim3(BB * 256), 256, 0, stream>>>(cls, Wq, bq, q);
    nq_kernel<<<dim3(BB * NH), 64, 0, stream>>>(q, nq);
    fused_kv<<<dim3(TT / 128, DD / 128, BB), 256, 0, stream>>>(
        Wkb, Wvb, Xt, bk, bv, q, nq, val);
    hipMemsetAsync(pooled, 0, POOL_FLOATS * sizeof(float), stream);
    hipMemsetAsync(out, 0, (size_t)out_size * sizeof(float), stream);
    pool_kernel<<<dim3(NROI, TSPLIT), 256, 0, stream>>>(val, rois, pooled);
    out_gemm<<<dim3(8, 4, 20), 256, 0, stream>>>(pooled, cw1, cb1, cw3, cb3,
                                                 cw7, cb7, cw9, cb9, out);
}

// Round 5
// 196.501 us; speedup vs baseline: 5.1854x; 1.0116x over previous
//
#include <hip/hip_runtime.h>
#include <hip/hip_bf16.h>
#include <math.h>

// Problem constants (fixed by setup_inputs)
#define BB   4
#define DD   1024
#define TT   2048
#define NH   8
#define DKH  128
#define NROI 128

typedef __attribute__((ext_vector_type(8))) __bf16 bf16x8;
typedef __attribute__((ext_vector_type(4))) float  f32x4;

// Workspace layout.
// fp32 region (floats):
#define OFF_Q    0                       // [B, D]            4096
#define OFF_NQ   4096                    // [B, H]            32
#define OFF_KV   131072                  // val bf16 [B][T][D] (16MB) lives here
#define OFF_POOL (131072 + 8388608)      // pooled: 655360 floats
#define POOL_FLOATS 655360
#define WS_F32_TOTAL (OFF_POOL + POOL_FLOATS)
// bf16 region at ws + WS_F32_TOTAL: Wkb [1M], Wvb [1M], Xt [8M] = 20 MB.

__device__ __forceinline__ float bfu2f(unsigned short u) {
    return __uint_as_float(((unsigned int)u) << 16);
}

// ---------------------------------------------------------------------------
// Kernel 1: q = cls @ Wq^T + bq (fp32, tiny)
__global__ __launch_bounds__(256) void qproj_kernel(
    const float* __restrict__ cls, const float* __restrict__ Wq,
    const float* __restrict__ bq, float* __restrict__ q)
{
    const int blk  = blockIdx.x;
    const int b    = blk >> 8;
    const int dg   = blk & 255;
    const int warp = threadIdx.x >> 6;
    const int lane = threadIdx.x & 63;
    const int d    = dg * 4 + warp;
    const float* crow = cls + (size_t)b * DD;
    const float* wrow = Wq + (size_t)d * DD;
    float acc = 0.f;
    for (int i = lane; i < DD; i += 64) acc += crow[i] * wrow[i];
    #pragma unroll
    for (int off = 32; off; off >>= 1) acc += __shfl_down(acc, off);
    if (lane == 0) q[(size_t)b * DD + d] = acc + bq[d];
}

__global__ __launch_bounds__(64) void nq_kernel(
    const float* __restrict__ q, float* __restrict__ nq)
{
    const int bh = blockIdx.x;
    const int lane = threadIdx.x;
    const float* base = q + (size_t)bh * DKH;
    float v0 = base[lane], v1 = base[lane + 64];
    float acc = v0 * v0 + v1 * v1;
    #pragma unroll
    for (int off = 32; off; off >>= 1) acc += __shfl_down(acc, off);
    if (lane == 0) nq[bh] = sqrtf(acc);
}

// ---------------------------------------------------------------------------
// Convert two fp32 weight matrices to bf16 (1M elements each), float4-wide.
__global__ __launch_bounds__(256) void convert_pair(
    const float* __restrict__ A, const float* __restrict__ B,
    __hip_bfloat16* __restrict__ Ab, __hip_bfloat16* __restrict__ Bb)
{
    const int i = blockIdx.x * 256 + threadIdx.x;
    float4 a = reinterpret_cast<const float4*>(A)[i];
    float4 b = reinterpret_cast<const float4*>(B)[i];
    union P4 { __hip_bfloat16 h[4]; ushort4 u; } pa, pb;
    pa.h[0] = __float2bfloat16(a.x); pa.h[1] = __float2bfloat16(a.y);
    pa.h[2] = __float2bfloat16(a.z); pa.h[3] = __float2bfloat16(a.w);
    pb.h[0] = __float2bfloat16(b.x); pb.h[1] = __float2bfloat16(b.y);
    pb.h[2] = __float2bfloat16(b.z); pb.h[3] = __float2bfloat16(b.w);
    reinterpret_cast<ushort4*>(Ab)[i] = pa.u;
    reinterpret_cast<ushort4*>(Bb)[i] = pb.u;
}

// ---------------------------------------------------------------------------
// X [B][D][T] f32 -> Xt [B][T][D] bf16.
__global__ __launch_bounds__(256) void transpose_convert(
    const float* __restrict__ X, __hip_bfloat16* __restrict__ Xt)
{
    __shared__ float tile[64][65];
    const int t0 = blockIdx.x * 64, d0 = blockIdx.y * 64, b = blockIdx.z;
    const int tid = threadIdx.x;
    const int g = tid >> 6, tl = tid & 63;
    const float* src = X + ((size_t)(b * DD + d0)) * TT + t0;
    #pragma unroll
    for (int i = 0; i < 16; ++i)
        tile[g * 16 + i][tl] = src[(size_t)(g * 16 + i) * TT + tl];
    __syncthreads();
    const int lane = tid & 63, w = tid >> 6;
    const int dq = (lane & 15) * 4;
    const int th = lane >> 4;
    __hip_bfloat16* dst = Xt + ((size_t)(b * TT + t0)) * DD + d0;
    #pragma unroll
    for (int i = 0; i < 4; ++i) {
        const int t = w * 4 + th + i * 16;
        union { __hip_bfloat16 h[4]; ushort4 u; } P;
        P.h[0] = __float2bfloat16(tile[dq + 0][t]);
        P.h[1] = __float2bfloat16(tile[dq + 1][t]);
        P.h[2] = __float2bfloat16(tile[dq + 2][t]);
        P.h[3] = __float2bfloat16(tile[dq + 3][t]);
        *reinterpret_cast<ushort4*>(&dst[(size_t)t * DD + dq]) = P.u;
    }
}

// ---------------------------------------------------------------------------
__device__ __forceinline__ void glds16(const __hip_bfloat16* g, __hip_bfloat16* l)
{
    __builtin_amdgcn_global_load_lds(
        (const __attribute__((address_space(1))) void*)g,
        (__attribute__((address_space(3))) void*)l, 16, 0, 0);
}

// Fused K-proj + cosine-attn + V-proj, 8-wave (512-thread) version.
//   k[t][m] = sum_d Wk[m][d]*Xt[b][t][d] + bk[m]        (m-tile = one head h)
//   dot(t)  = sum_m k[t][m]*q[b][m0+m];  sq(t) = sum_m k[t][m]^2   (block-local)
//   p(t)    = exp(|dot / max(nq[b,h]*sqrt(sq), eps)|)
//   val[b][t][m] = bf16((sum_d Wv[m][d]*Xt[b][t][d] + bv[m]) * p(t))
// 128x128 tile, BK=32. 8 waves: wr = w>>2 (m-half 64), wc = w&3 (t-quarter 32).
// Per wave: ak[4][2] + av[4][2] acc (64 VGPR), 10 ds_read_b128 / 16 MFMA per step.
__global__ __launch_bounds__(512) void fused_kv(
    const __hip_bfloat16* __restrict__ Wkb,
    const __hip_bfloat16* __restrict__ Wvb,
    const __hip_bfloat16* __restrict__ Xt,
    const float* __restrict__ bk, const float* __restrict__ bv,
    const float* __restrict__ q,  const float* __restrict__ nq,
    __hip_bfloat16* __restrict__ val)
{
    const int t0 = blockIdx.x * 128;
    const int m0 = blockIdx.y * 128;
    const int b  = blockIdx.z;

    __shared__ __hip_bfloat16 AsK[128 * 32];
    __shared__ __hip_bfloat16 AsV[128 * 32];
    __shared__ __hip_bfloat16 Bs[128 * 32];
    __shared__ float qs[128];
    __shared__ float rdot[2][128];   // [wr][t_local]
    __shared__ float rsq[2][128];
    __shared__ float p_lds[128];

    const int tid  = threadIdx.x;
    const int lane = tid & 63;
    const int w    = tid >> 6;           // 0..7
    const int wr   = w >> 2;             // m-half
    const int wc   = w & 3;              // t-quarter

    if (tid < 128) qs[tid] = q[(size_t)b * DD + m0 + tid];

    // Staging: one glds16 per tile per K-step. 512 threads x 16B = 8KB tile.
    // Thread covers tile row (tid>>2), slot (tid&3); swizzled k-group
    // g = (tid&3) ^ ((row>>1)&3); wave-uniform LDS base = w*16 rows.
    const int st_row = tid >> 2;                       // 0..127
    const int st_g   = (tid & 3) ^ ((st_row >> 1) & 3);

    const __hip_bfloat16* WkS = Wkb + (size_t)(m0 + st_row) * DD + st_g * 8;
    const __hip_bfloat16* WvS = Wvb + (size_t)(m0 + st_row) * DD + st_g * 8;
    const __hip_bfloat16* XS  = Xt + ((size_t)(b * TT + t0 + st_row)) * DD + st_g * 8;
    __hip_bfloat16* K0 = AsK + (w * 16) * 32;
    __hip_bfloat16* V0 = AsV + (w * 16) * 32;
    __hip_bfloat16* B0 = Bs  + (w * 16) * 32;

    f32x4 ak[4][2], av[4][2];
    #pragma unroll
    for (int i = 0; i < 4; ++i)
        #pragma unroll
        for (int j = 0; j < 2; ++j) {
            ak[i][j] = (f32x4){0.f, 0.f, 0.f, 0.f};
            av[i][j] = (f32x4){0.f, 0.f, 0.f, 0.f};
        }

    for (int k0 = 0; k0 < DD; k0 += 32) {
        glds16(WkS + k0, K0);
        glds16(WvS + k0, V0);
        glds16(XS  + k0, B0);
        __syncthreads();

        const int g = lane >> 4;
        bf16x8 bfx[2], afk[4], afv[4];
        #pragma unroll
        for (int fn = 0; fn < 2; ++fn) {
            const int r = wc * 32 + fn * 16 + (lane & 15);
            const int s = g ^ ((r >> 1) & 3);
            bfx[fn] = *reinterpret_cast<const bf16x8*>(&Bs[r * 32 + s * 8]);
        }
        #pragma unroll
        for (int fm = 0; fm < 4; ++fm) {
            const int r = wr * 64 + fm * 16 + (lane & 15);
            const int s = g ^ ((r >> 1) & 3);
            afk[fm] = *reinterpret_cast<const bf16x8*>(&AsK[r * 32 + s * 8]);
            afv[fm] = *reinterpret_cast<const bf16x8*>(&AsV[r * 32 + s * 8]);
        }
        #pragma unroll
        for (int fm = 0; fm < 4; ++fm)
            #pragma unroll
            for (int fn = 0; fn < 2; ++fn)
                ak[fm][fn] = __builtin_amdgcn_mfma_f32_16x16x32_bf16(
                    afk[fm], bfx[fn], ak[fm][fn], 0, 0, 0);
        #pragma unroll
        for (int fm = 0; fm < 4; ++fm)
            #pragma unroll
            for (int fn = 0; fn < 2; ++fn)
                av[fm][fn] = __builtin_amdgcn_mfma_f32_16x16x32_bf16(
                    afv[fm], bfx[fn], av[fm][fn], 0, 0, 0);
        __syncthreads();
    }

    // --- attention scalar per t ---
    // C/D: t_local = wc*32 + fn*16 + (lane&15); m_local = wr*64 + fm*16 + (lane>>4)*4 + r
    const int lg = lane >> 4;
    #pragma unroll
    for (int fn = 0; fn < 2; ++fn) {
        float dp = 0.f, sp = 0.f;
        #pragma unroll
        for (int fm = 0; fm < 4; ++fm) {
            const int mb = wr * 64 + fm * 16 + lg * 4;
            #pragma unroll
            for (int r = 0; r < 4; ++r) {
                const float kv = ak[fm][fn][r] + bk[m0 + mb + r];
                dp += kv * qs[mb + r];
                sp += kv * kv;
            }
        }
        dp += __shfl_xor(dp, 16); sp += __shfl_xor(sp, 16);
        dp += __shfl_xor(dp, 32); sp += __shfl_xor(sp, 32);
        if (lane < 16) {
            rdot[wr][wc * 32 + fn * 16 + lane] = dp;
            rsq[wr][wc * 32 + fn * 16 + lane]  = sp;
        }
    }
    __syncthreads();
    if (tid < 128) {
        const float dd = rdot[0][tid] + rdot[1][tid];
        const float ss = rsq[0][tid] + rsq[1][tid];
        const int head = m0 >> 7;
        const float c = dd / fmaxf(nq[b * NH + head] * sqrtf(ss), 1e-8f);
        p_lds[tid] = expf(fabsf(c));
    }
    __syncthreads();

    // --- val write: (av + bv) * p, bf16, [B][T][D] ---
    float pv[2];
    #pragma unroll
    for (int fn = 0; fn < 2; ++fn)
        pv[fn] = p_lds[wc * 32 + fn * 16 + (lane & 15)];

    const int tbase = t0 + wc * 32 + (lane & 15);
    #pragma unroll
    for (int fm = 0; fm < 4; ++fm) {
        const int m = m0 + wr * 64 + fm * 16 + lg * 4;
        const float4 b4 = *reinterpret_cast<const float4*>(&bv[m]);
        #pragma unroll
        for (int fn = 0; fn < 2; ++fn) {
            const int t = tbase + fn * 16;
            const f32x4 a = av[fm][fn];
            const float pf = pv[fn];
            union { __hip_bfloat16 h[4]; ushort4 u; } P;
            P.h[0] = __float2bfloat16((a[0] + b4.x) * pf);
            P.h[1] = __float2bfloat16((a[1] + b4.y) * pf);
            P.h[2] = __float2bfloat16((a[2] + b4.z) * pf);
            P.h[3] = __float2bfloat16((a[3] + b4.w) * pf);
            *reinterpret_cast<ushort4*>(&val[((size_t)(b * TT + t)) * DD + m]) = P.u;
        }
    }
}

// ---------------------------------------------------------------------------
// ROI pool over val [B][T][D] bf16. Grid (NROI, TSPLIT).
#define TSPLIT 16
__global__ __launch_bounds__(256) void pool_kernel(
    const __hip_bfloat16* __restrict__ val, const int* __restrict__ rois,
    float* __restrict__ pooled)
{
    const int n     = blockIdx.x;
    const int split = blockIdx.y;
    const int tid   = threadIdx.x;
    const int sc    = tid >> 6;
    const int c4    = tid * 4;
    const int cl    = (tid & 63) * 4;

    const int nbt[4]  = {1, 3, 7, 9};
    const int offt[4] = {0, 32768, 131072, 360448};
    const int nb  = nbt[sc];
    const int off = offt[sc];

    const int bidx = rois[n * 3 + 0];
    const int s    = rois[n * 3 + 1];
    const int e    = rois[n * 3 + 2];
    const int L    = e - s;

    const int ts = s + (split * L) / TSPLIT;
    const int te = s + ((split + 1) * L) / TSPLIT;
    if (te <= ts) return;

    const int b_lo = ((ts - s) * nb) / L;
    const int b_hi = ((te - s) * nb - 1) / L;

    const __hip_bfloat16* vb = val + (size_t)bidx * TT * DD + c4;
    float* po = pooled + off + ((size_t)n * 256 + cl) * nb;

    for (int bin = b_lo; bin <= b_hi; ++bin) {
        const int bs = s + (bin * L) / nb;
        const int be = s + ((bin + 1) * L + nb - 1) / nb;
        const int lo = max(bs, ts), hi = min(be, te);
        if (hi <= lo) continue;
        float a0 = 0.f, a1 = 0.f, a2 = 0.f, a3 = 0.f;
        for (int t = lo; t < hi; ++t) {
            const ushort4 u = *reinterpret_cast<const ushort4*>(&vb[(size_t)t * DD]);
            a0 += bfu2f(u.x); a1 += bfu2f(u.y);
            a2 += bfu2f(u.z); a3 += bfu2f(u.w);
        }
        const float inv = 1.0f / (float)(be - bs);
        atomicAdd(po + bin,          a0 * inv);
        atomicAdd(po + nb + bin,     a1 * inv);
        atomicAdd(po + 2 * nb + bin, a2 * inv);
        atomicAdd(po + 3 * nb + bin, a3 * inv);
    }
}

// ---------------------------------------------------------------------------
// Final NT GEMM, K-split. Grid (8, 4, 20). atomicAdd partials into zeroed out.
__global__ __launch_bounds__(256) void out_gemm(
    const float* __restrict__ pooled,
    const float* __restrict__ w1, const float* __restrict__ b1,
    const float* __restrict__ w3, const float* __restrict__ b3,
    const float* __restrict__ w7, const float* __restrict__ b7,
    const float* __restrict__ w9, const float* __restrict__ b9,
    float* __restrict__ out)
{
    const int z = blockIdx.z;
    int sc, kc;
    if      (z == 0)  { sc = 0; kc = 0; }
    else if (z < 4)   { sc = 1; kc = z - 1; }
    else if (z < 11)  { sc = 2; kc = z - 4; }
    else              { sc = 3; kc = z - 11; }

    int nb, off; const float* W; const float* bias;
    switch (sc) {
        case 0:  nb = 1; off = 0;      W = w1; bias = b1; break;
        case 1:  nb = 3; off = 32768;  W = w3; bias = b3; break;
        case 2:  nb = 7; off = 131072; W = w7; bias = b7; break;
        default: nb = 9; off = 360448; W = w9; bias = b9; break;
    }
    const int Kj = 256 * nb;
    const float* P = pooled + off;

    const int o0 = blockIdx.x * 32;
    const int n0 = blockIdx.y * 32;
    const int kbase = kc * 256;

    __shared__ float Ps[32][33];
    __shared__ float Ws[32][33];

    const int tid = threadIdx.x;
    const int tx = tid & 15, ty = tid >> 4;
    float acc[2][2] = {};

    for (int k0 = kbase; k0 < kbase + 256; k0 += 32) {
        #pragma unroll
        for (int i = 0; i < 4; ++i) {
            const int li = tid + i * 256;
            const int r = li >> 5, k = li & 31;
            Ps[r][k] = P[(size_t)(n0 + r) * Kj + k0 + k];
            Ws[r][k] = W[(size_t)(o0 + r) * Kj + k0 + k];
        }
        __syncthreads();
        #pragma unroll
        for (int k = 0; k < 32; ++k) {
            const float p0 = Ps[ty][k],  p1 = Ps[ty + 16][k];
            const float w0 = Ws[tx][k],  w1v = Ws[tx + 16][k];
            acc[0][0] = fmaf(p0, w0,  acc[0][0]);
            acc[0][1] = fmaf(p0, w1v, acc[0][1]);
            acc[1][0] = fmaf(p1, w0,  acc[1][0]);
            acc[1][1] = fmaf(p1, w1v, acc[1][1]);
        }
        __syncthreads();
    }
    #pragma unroll
    for (int i = 0; i < 2; ++i) {
        const int n = n0 + ty + 16 * i;
        #pragma unroll
        for (int jj = 0; jj < 2; ++jj) {
            const int o = o0 + tx + 16 * jj;
            const float add = (kc == 0) ? bias[o] : 0.f;
            atomicAdd(&out[(size_t)n * DD + sc * 256 + o], acc[i][jj] + add);
        }
    }
}

// ---------------------------------------------------------------------------
extern "C" void kernel_launch(void* const* d_in, const int* in_sizes, int n_in,
                              void* d_out, int out_size, void* d_ws, size_t ws_size,
                              hipStream_t stream)
{
    const float* inp  = (const float*)d_in[0];   // [B, D, T]
    const float* cls  = (const float*)d_in[1];   // [B, D]
    const int*   rois = (const int*)  d_in[2];   // [N, 3]
    const float* Wq   = (const float*)d_in[3];
    const float* bq   = (const float*)d_in[4];
    const float* Wk   = (const float*)d_in[5];
    const float* bk   = (const float*)d_in[6];
    const float* Wv   = (const float*)d_in[7];
    const float* bv   = (const float*)d_in[8];
    const float* cw1  = (const float*)d_in[9];  const float* cb1 = (const float*)d_in[10];
    const float* cw3  = (const float*)d_in[11]; const float* cb3 = (const float*)d_in[12];
    const float* cw7  = (const float*)d_in[13]; const float* cb7 = (const float*)d_in[14];
    const float* cw9  = (const float*)d_in[15]; const float* cb9 = (const float*)d_in[16];

    float* out = (float*)d_out;
    float* ws  = (float*)d_ws;
    float* q      = ws + OFF_Q;
    float* nq     = ws + OFF_NQ;
    __hip_bfloat16* val = (__hip_bfloat16*)(ws + OFF_KV);  // bf16 [B][T][D]
    float* pooled = ws + OFF_POOL;
    __hip_bfloat16* bfb = (__hip_bfloat16*)(ws + WS_F32_TOTAL);
    __hip_bfloat16* Wkb = bfb;
    __hip_bfloat16* Wvb = bfb + 1048576;
    __hip_bfloat16* Xt  = bfb + 2097152;               // [B][T][D]

    convert_pair<<<dim3(1024), 256, 0, stream>>>(Wk, Wv, Wkb, Wvb);
    transpose_convert<<<dim3(TT / 64, DD / 64, BB), 256, 0, stream>>>(inp, Xt);
    qproj_kernel<<<dim3(BB * 256), 256, 0, stream>>>(cls, Wq, bq, q);
    nq_kernel<<<dim3(BB * NH), 64, 0, stream>>>(q, nq);
    fused_kv<<<dim3(TT / 128, DD / 128, BB), 512, 0, stream>>>(
        Wkb, Wvb, Xt, bk, bv, q, nq, val);
    hipMemsetAsync(pooled, 0, POOL_FLOATS * sizeof(float), stream);
    hipMemsetAsync(out, 0, (size_t)out_size * sizeof(float), stream);
    pool_kernel<<<dim3(NROI, TSPLIT), 256, 0, stream>>>(val, rois, pooled);
    out_gemm<<<dim3(8, 4, 20), 256, 0, stream>>>(pooled, cw1, cb1, cw3, cb3,
                                                 cw7, cb7, cw9, cb9, out);
}